// Round 6
// baseline (263.798 us; speedup 1.0000x reference)
//
#include <hip/hip_runtime.h>
#include <hip/hip_cooperative_groups.h>

namespace cg = cooperative_groups;

#define BB 4
#define DD 81
#define HH 256
#define WW 256
#define HW (HH*WW)
#define HW4 (HW/4)        // 16384 float4 per (b) image plane row-major
#define NCOL4 (BB*HW4)    // 65536 float4-columns
#define NTHREADS (2*NCOL4)    // 131072 = 512 blocks * 256

__device__ __forceinline__ float4 f4min(float4 a, float4 b) {
    return float4{fminf(a.x, b.x), fminf(a.y, b.y), fminf(a.z, b.z), fminf(a.w, b.w)};
}

// ---------------------------------------------------------------------------
// Wave-parallel bidirectional linear-recurrence scan over 256 elements.
// m_j = c_j + e_j*m_{j-1}; operator (a,b) composes as cur∘prev =
// (a_c*a_p, a_c*b_p + b_c). g_j = e_j*m_{j-1} accumulated for both directions.
// (validated in rounds 2-4)
// ---------------------------------------------------------------------------
__device__ __forceinline__ void wave_scan_bidir(
        int lane, const float c[4], const float ef[4], const float eb[4], float g[4]) {
    float A = 1.f, B = 0.f;
    #pragma unroll
    for (int j = 0; j < 4; ++j) { B = ef[j] * B + c[j]; A = ef[j] * A; }
    #pragma unroll
    for (int d = 1; d < 64; d <<= 1) {
        float Ap = __shfl_up(A, d);
        float Bp = __shfl_up(B, d);
        if (lane >= d) { B = A * Bp + B; A = A * Ap; }
    }
    float m_in = __shfl_up(B, 1);
    if (lane == 0) m_in = 0.f;
    float m = m_in;
    #pragma unroll
    for (int j = 0; j < 4; ++j) { float t = ef[j] * m; g[j] = t; m = c[j] + t; }

    A = 1.f; B = 0.f;
    #pragma unroll
    for (int j = 3; j >= 0; --j) { B = eb[j] * B + c[j]; A = eb[j] * A; }
    #pragma unroll
    for (int d = 1; d < 64; d <<= 1) {
        float An = __shfl_down(A, d);
        float Bn = __shfl_down(B, d);
        if (lane + d < 64) { B = A * Bn + B; A = A * An; }
    }
    m_in = __shfl_down(B, 1);
    if (lane == 63) m_in = 0.f;
    m = m_in;
    #pragma unroll
    for (int j = 3; j >= 0; --j) { float t = eb[j] * m; g[j] += t; m = c[j] + t; }
}

// ---------------------------------------------------------------------------
// Fused cooperative kernel, 512 blocks x 256 = 131072 threads (2 blocks/CU
// needed; kernel is light so >=4 fit -- safe co-residency margin).
// Thread pair (2t, 2t+1) owns float4-column col4 = t: even thread handles
// d in [0,40), odd d in [40,81).
//   phase 1: per-half min over d (16-deep float4 batches for MLP),
//            pair-combine via __shfl_xor, even lane writes cmin. (85 MB HBM)
//   phase 2: 2048 waves: 1024 horizontal row scans + 1024 vertical col scans.
//   phase 3: g = gh+gv (L2); out = 4*cost + g, cost re-read from L3,
//            out written once. (85 MB write + L3 read)
// ---------------------------------------------------------------------------
__global__ __launch_bounds__(256, 2) void k_fused(
        const float* __restrict__ cost, const float* __restrict__ edge,
        float* __restrict__ out, float* __restrict__ ws) {
    float* gh   = ws;
    float* gv   = ws + (size_t)BB * HW;
    float* cmin = ws + (size_t)2 * BB * HW;

    const int t    = blockIdx.x * blockDim.x + threadIdx.x;  // [0, NTHREADS)
    const int col4 = t >> 1;
    const int half = t & 1;
    const int b    = col4 >> 14;          // col4 / HW4
    const int hw4  = col4 & (HW4 - 1);
    const int d0   = half * 40;           // 40 or 41 d's per half
    const size_t colbase = (size_t)b * DD * HW4 + hw4;

    // ---- phase 1: partial min over this half's d-range ----
    {
        const float4* s = reinterpret_cast<const float4*>(cost) + colbase + (size_t)d0 * HW4;
        float4 m = {3.4e38f, 3.4e38f, 3.4e38f, 3.4e38f};
        #pragma unroll
        for (int B0 = 0; B0 < 32; B0 += 16) {
            float4 v[16];
            #pragma unroll
            for (int k = 0; k < 16; ++k) v[k] = s[(size_t)(B0 + k) * HW4];
            #pragma unroll
            for (int k = 0; k < 16; ++k) m = f4min(m, v[k]);
        }
        {
            float4 v[8];
            #pragma unroll
            for (int k = 0; k < 8; ++k) v[k] = s[(size_t)(32 + k) * HW4];
            #pragma unroll
            for (int k = 0; k < 8; ++k) m = f4min(m, v[k]);
        }
        if (half) m = f4min(m, s[(size_t)40 * HW4]);
        // pair-combine: lanes (2i, 2i+1) exchange
        float4 o;
        o.x = fminf(m.x, __shfl_xor(m.x, 1));
        o.y = fminf(m.y, __shfl_xor(m.y, 1));
        o.z = fminf(m.z, __shfl_xor(m.z, 1));
        o.w = fminf(m.w, __shfl_xor(m.w, 1));
        if (!half) reinterpret_cast<float4*>(cmin)[col4] = o;
    }

    __threadfence();
    cg::this_grid().sync();

    // ---- phase 2: directional scans (all 2048 waves busy) ----
    {
        const int wave = t >> 6;
        const int lane = t & 63;
        float c[4], ef[4], eb[4], g[4];
        if (wave < BB * HH) {                       // horizontal rows
            int sb = wave >> 8, h = wave & (HH - 1);
            size_t row = (size_t)sb * HW + (size_t)h * WW;
            float4 c4 = reinterpret_cast<const float4*>(cmin + row)[lane];
            float4 f4 = reinterpret_cast<const float4*>(edge + ((size_t)sb * 4 + 0) * HW + (size_t)h * WW)[lane];
            float4 b4 = reinterpret_cast<const float4*>(edge + ((size_t)sb * 4 + 1) * HW + (size_t)h * WW)[lane];
            c[0]=c4.x; c[1]=c4.y; c[2]=c4.z; c[3]=c4.w;
            ef[0]=f4.x; ef[1]=f4.y; ef[2]=f4.z; ef[3]=f4.w;
            eb[0]=b4.x; eb[1]=b4.y; eb[2]=b4.z; eb[3]=b4.w;
            wave_scan_bidir(lane, c, ef, eb, g);
            float4 o = {g[0], g[1], g[2], g[3]};
            reinterpret_cast<float4*>(gh + row)[lane] = o;
        } else {                                    // vertical columns
            int wv = wave - BB * HH;
            int sb = wv >> 8, w = wv & (WW - 1);
            const float* cm = cmin + (size_t)sb * HW + w;
            const float* e2 = edge + ((size_t)sb * 4 + 2) * HW + w;
            const float* e3 = edge + ((size_t)sb * 4 + 3) * HW + w;
            int r0 = lane * 4;
            #pragma unroll
            for (int j = 0; j < 4; ++j) {
                size_t off = (size_t)(r0 + j) * WW;
                c[j]  = cm[off];
                ef[j] = e2[off];
                eb[j] = e3[off];
            }
            wave_scan_bidir(lane, c, ef, eb, g);
            float* go = gv + (size_t)sb * HW + w;
            #pragma unroll
            for (int j = 0; j < 4; ++j) go[(size_t)(r0 + j) * WW] = g[j];
        }
    }

    __threadfence();
    cg::this_grid().sync();

    // ---- phase 3: out = 4*cost + (gh+gv), this half's d-range ----
    {
        float4 a = reinterpret_cast<const float4*>(gh)[col4];
        float4 v = reinterpret_cast<const float4*>(gv)[col4];
        float4 g = {a.x + v.x, a.y + v.y, a.z + v.z, a.w + v.w};
        const float4* s = reinterpret_cast<const float4*>(cost) + colbase + (size_t)d0 * HW4;
        float4*       o = reinterpret_cast<float4*>(out)        + colbase + (size_t)d0 * HW4;
        const int n = 40 + half;
        #pragma unroll 8
        for (int d = 0; d < n; ++d) {
            float4 c = s[(size_t)d * HW4];
            float4 r;
            r.x = fmaf(c.x, 4.f, g.x);
            r.y = fmaf(c.y, 4.f, g.y);
            r.z = fmaf(c.z, 4.f, g.z);
            r.w = fmaf(c.w, 4.f, g.w);
            o[(size_t)d * HW4] = r;
        }
    }
}

extern "C" void kernel_launch(void* const* d_in, const int* in_sizes, int n_in,
                              void* d_out, int out_size, void* d_ws, size_t ws_size,
                              hipStream_t stream) {
    const float* cost = (const float*)d_in[0];
    const float* edge = (const float*)d_in[1];
    float* out = (float*)d_out;
    float* ws  = (float*)d_ws;   // gh [1MB] | gv [1MB] | cmin [1MB]

    void* args[] = {(void*)&cost, (void*)&edge, (void*)&out, (void*)&ws};
    hipLaunchCooperativeKernel((void*)k_fused, dim3(NTHREADS / 256), dim3(256),
                               args, 0, stream);
}

// Round 7
// 52.397 us; speedup vs baseline: 5.0346x; 5.0346x over previous
//
#include <hip/hip_runtime.h>

#define BB 4
#define DD 81
#define HH 256
#define WW 256
#define HW (HH*WW)
#define HW4 (HW/4)        // 16384 float4 per image plane
#define N4 (BB*HW4)       // 65536 float4-columns

__device__ __forceinline__ float4 f4min(float4 a, float4 b) {
    return float4{fminf(a.x, b.x), fminf(a.y, b.y), fminf(a.z, b.z), fminf(a.w, b.w)};
}

// ---------------------------------------------------------------------------
// Kernel 1: cmin = min over d of cost.
// Block = 64 float4-columns x 4 d-chunks. tid = g*64 + c:
//   lane c -> column (coalesced 1KB/wave), g -> contiguous d-chunk
//   (g=0: d[0,21), g=1: [21,41), g=2: [41,61), g=3: [61,81)).
// Explicit 5-deep float4 batches keep 5 loads in flight per thread;
// 1024 blocks = 4/CU = 16 waves/CU -> ~80 KB in flight per CU (BW-bound).
// LDS combine of the 4 partials; no global partial traffic.
// ---------------------------------------------------------------------------
__global__ __launch_bounds__(256) void k_cmin(const float* __restrict__ cost,
                                              float* __restrict__ cmin) {
    __shared__ float4 part[256];
    const int c    = threadIdx.x & 63;
    const int g    = threadIdx.x >> 6;
    const int col4 = blockIdx.x * 64 + c;          // [0, N4)
    const int b    = col4 >> 14;                   // col4 / HW4
    const int hw4  = col4 & (HW4 - 1);
    const float4* s = reinterpret_cast<const float4*>(cost) + (size_t)b * DD * HW4 + hw4;

    const int d0 = (g == 0) ? 0 : g * 20 + 1;      // 0,21,41,61
    const float4* p = s + (size_t)d0 * HW4;
    float4 m = {3.4e38f, 3.4e38f, 3.4e38f, 3.4e38f};
    #pragma unroll
    for (int B0 = 0; B0 < 20; B0 += 5) {
        float4 v[5];
        #pragma unroll
        for (int j = 0; j < 5; ++j) v[j] = p[(size_t)(B0 + j) * HW4];
        #pragma unroll
        for (int j = 0; j < 5; ++j) m = f4min(m, v[j]);
    }
    if (g == 0) m = f4min(m, p[(size_t)20 * HW4]); // the 81st plane

    part[threadIdx.x] = m;
    __syncthreads();
    if (g == 0) {
        float4 r = f4min(f4min(part[c], part[64 + c]),
                         f4min(part[128 + c], part[192 + c]));
        reinterpret_cast<float4*>(cmin)[col4] = r;
    }
}

// ---------------------------------------------------------------------------
// Wave-parallel bidirectional linear-recurrence scan over 256 elements.
// m_j = c_j + e_j*m_{j-1}; operator (a,b) composes as cur∘prev =
// (a_c*a_p, a_c*b_p + b_c). g_j = e_j*m_{j-1} accumulated for both dirs.
// (validated rounds 2-4)
// ---------------------------------------------------------------------------
__device__ __forceinline__ void wave_scan_bidir(
        int lane, const float c[4], const float ef[4], const float eb[4], float g[4]) {
    float A = 1.f, B = 0.f;
    #pragma unroll
    for (int j = 0; j < 4; ++j) { B = ef[j] * B + c[j]; A = ef[j] * A; }
    #pragma unroll
    for (int d = 1; d < 64; d <<= 1) {
        float Ap = __shfl_up(A, d);
        float Bp = __shfl_up(B, d);
        if (lane >= d) { B = A * Bp + B; A = A * Ap; }
    }
    float m_in = __shfl_up(B, 1);
    if (lane == 0) m_in = 0.f;
    float m = m_in;
    #pragma unroll
    for (int j = 0; j < 4; ++j) { float t = ef[j] * m; g[j] = t; m = c[j] + t; }

    A = 1.f; B = 0.f;
    #pragma unroll
    for (int j = 3; j >= 0; --j) { B = eb[j] * B + c[j]; A = eb[j] * A; }
    #pragma unroll
    for (int d = 1; d < 64; d <<= 1) {
        float An = __shfl_down(A, d);
        float Bn = __shfl_down(B, d);
        if (lane + d < 64) { B = A * Bn + B; A = A * An; }
    }
    m_in = __shfl_down(B, 1);
    if (lane == 63) m_in = 0.f;
    m = m_in;
    #pragma unroll
    for (int j = 3; j >= 0; --j) { float t = eb[j] * m; g[j] += t; m = c[j] + t; }
}

// ---------------------------------------------------------------------------
// Kernel 2: waves [0,1024): horizontal rows (ch 0 fwd, ch 1 bwd) -> gh
//           waves [1024,2048): vertical cols (ch 2 down, ch 3 up) -> gv
// ---------------------------------------------------------------------------
__global__ void k_scan(const float* __restrict__ cmin, const float* __restrict__ edge,
                       float* __restrict__ gh, float* __restrict__ gv) {
    int tid  = blockIdx.x * blockDim.x + threadIdx.x;
    int wave = tid >> 6;
    int lane = tid & 63;
    float c[4], ef[4], eb[4], g[4];
    if (wave < BB * HH) {
        int b = wave >> 8, h = wave & (HH - 1);
        size_t row = (size_t)b * HW + (size_t)h * WW;
        float4 c4  = reinterpret_cast<const float4*>(cmin + row)[lane];
        float4 f4  = reinterpret_cast<const float4*>(edge + ((size_t)b * 4 + 0) * HW + (size_t)h * WW)[lane];
        float4 b4  = reinterpret_cast<const float4*>(edge + ((size_t)b * 4 + 1) * HW + (size_t)h * WW)[lane];
        c[0]=c4.x; c[1]=c4.y; c[2]=c4.z; c[3]=c4.w;
        ef[0]=f4.x; ef[1]=f4.y; ef[2]=f4.z; ef[3]=f4.w;
        eb[0]=b4.x; eb[1]=b4.y; eb[2]=b4.z; eb[3]=b4.w;
        wave_scan_bidir(lane, c, ef, eb, g);
        float4 o = {g[0], g[1], g[2], g[3]};
        reinterpret_cast<float4*>(gh + row)[lane] = o;
    } else if (wave < 2 * BB * HH) {
        int wv = wave - BB * HH;
        int b = wv >> 8, w = wv & (WW - 1);
        const float* cm = cmin + (size_t)b * HW + w;
        const float* e2 = edge + ((size_t)b * 4 + 2) * HW + w;
        const float* e3 = edge + ((size_t)b * 4 + 3) * HW + w;
        int r0 = lane * 4;
        #pragma unroll
        for (int j = 0; j < 4; ++j) {
            size_t off = (size_t)(r0 + j) * WW;
            c[j]  = cm[off];
            ef[j] = e2[off];
            eb[j] = e3[off];
        }
        wave_scan_bidir(lane, c, ef, eb, g);
        float* go = gv + (size_t)b * HW + w;
        #pragma unroll
        for (int j = 0; j < 4; ++j) go[(size_t)(r0 + j) * WW] = g[j];
    }
}

// ---------------------------------------------------------------------------
// Kernel 3: out[b,d,h,w] = 4*cost[b,d,h,w] + gh[b,h,w] + gv[b,h,w]
// ---------------------------------------------------------------------------
__global__ void k_out(const float* __restrict__ cost, const float* __restrict__ gh,
                      const float* __restrict__ gv, float* __restrict__ out) {
    int i = blockIdx.x * blockDim.x + threadIdx.x;
    const int n4 = BB * DD * HW / 4;
    if (i >= n4) return;
    int base = i << 2;
    int b    = base / (DD * HW);
    int rem  = base % (DD * HW);
    int hw   = rem % HW;
    float4 c = reinterpret_cast<const float4*>(cost)[i];
    int gi   = (b * HW + hw) >> 2;
    float4 a = reinterpret_cast<const float4*>(gh)[gi];
    float4 v = reinterpret_cast<const float4*>(gv)[gi];
    float4 o;
    o.x = fmaf(c.x, 4.f, a.x + v.x);
    o.y = fmaf(c.y, 4.f, a.y + v.y);
    o.z = fmaf(c.z, 4.f, a.z + v.z);
    o.w = fmaf(c.w, 4.f, a.w + v.w);
    reinterpret_cast<float4*>(out)[i] = o;
}

extern "C" void kernel_launch(void* const* d_in, const int* in_sizes, int n_in,
                              void* d_out, int out_size, void* d_ws, size_t ws_size,
                              hipStream_t stream) {
    const float* cost = (const float*)d_in[0];
    const float* edge = (const float*)d_in[1];
    float* out = (float*)d_out;

    // ws layout: gh [1MB] | gv [1MB] | cmin [1MB]
    float* gh   = (float*)d_ws;
    float* gv   = gh + (size_t)BB * HW;
    float* cmin = gv + (size_t)BB * HW;

    {   // 1: cmin, 1024 blocks x 256
        k_cmin<<<dim3(N4 / 64), dim3(256), 0, stream>>>(cost, cmin);
    }
    {   // 2: scans, 2048 waves = 131072 threads
        int n = 2 * BB * HH * 64;
        k_scan<<<dim3((n + 255) / 256), dim3(256), 0, stream>>>(cmin, edge, gh, gv);
    }
    {   // 3: output
        int n4 = BB * DD * HW / 4;
        k_out<<<dim3((n4 + 255) / 256), dim3(256), 0, stream>>>(cost, gh, gv, out);
    }
}